// Round 6
// baseline (183.457 us; speedup 1.0000x reference)
//
#include <hip/hip_runtime.h>
#include <hip/hip_bf16.h>

#define P_TOT 32768   // H*W
#define O_QKV 768

using f32x4   = float  __attribute__((ext_vector_type(4)));
using bf16x8  = __bf16 __attribute__((ext_vector_type(8)));
using ushort8 = unsigned short __attribute__((ext_vector_type(8)));

typedef __attribute__((address_space(1))) void* gptr_t;
typedef __attribute__((address_space(3))) void* sptr_t;
// async global->LDS, 16B per lane, dest = uniform base + lane*16
#define GLL16(g, l) __builtin_amdgcn_global_load_lds((gptr_t)(g), (sptr_t)(l), 16, 0, 0)

__device__ __forceinline__ ushort f2b(float f) {
    __hip_bfloat16 h = __float2bfloat16(f);   // RNE
    return *reinterpret_cast<ushort*>(&h);
}
__device__ __forceinline__ float b2f(ushort u) {
    return __uint_as_float(((unsigned)u) << 16);   // exact
}

// ---------------------------------------------------------------------------
// prep: cast weights to bf16 (Wqkv = [wq;wk;wv] rows, (768,256)), pack biases
// ---------------------------------------------------------------------------
__global__ __launch_bounds__(256) void prep_w(
    const float* __restrict__ wq, const float* __restrict__ wk,
    const float* __restrict__ wv, const float* __restrict__ wo,
    const float* __restrict__ bq, const float* __restrict__ bk,
    const float* __restrict__ bv,
    ushort* __restrict__ Wqkv, ushort* __restrict__ Wo, float* __restrict__ Bqkv)
{
    const int i = blockIdx.x * 256 + threadIdx.x;   // grid 256 -> i < 65536
    Wqkv[i]           = f2b(wq[i]);
    Wqkv[65536 + i]   = f2b(wk[i]);
    Wqkv[131072 + i]  = f2b(wv[i]);
    Wo[i]             = f2b(wo[i]);
    if (i < 256) { Bqkv[i] = bq[i]; Bqkv[256 + i] = bk[i]; Bqkv[512 + i] = bv[i]; }
}

// ---------------------------------------------------------------------------
// transpose: x (256, 32768) fp32 -> Xt (32768, 256) bf16
// ---------------------------------------------------------------------------
__global__ __launch_bounds__(256) void transpose_x(
    const float* __restrict__ x, ushort* __restrict__ Xt)
{
    __shared__ float ts[64][65];
    const int p0 = blockIdx.x * 64, c0 = blockIdx.y * 64;
    const int t = threadIdx.x;
    const int pl = t & 63, cl = t >> 6;
    #pragma unroll
    for (int i = 0; i < 16; ++i)
        ts[cl + 4 * i][pl] = x[(size_t)(c0 + cl + 4 * i) * P_TOT + p0 + pl];
    __syncthreads();
    const int pr = t >> 4, cc = (t & 15) * 4;
    #pragma unroll
    for (int i = 0; i < 4; ++i) {
        const int p = pr + 16 * i;
        ushort4 u;
        u.x = f2b(ts[cc + 0][p]); u.y = f2b(ts[cc + 1][p]);
        u.z = f2b(ts[cc + 2][p]); u.w = f2b(ts[cc + 3][p]);
        *(ushort4*)&Xt[(size_t)(p0 + p) * 256 + c0 + cc] = u;
    }
}

// ---------------------------------------------------------------------------
// GEMM1: QKV[p][o] = sum_c Xt[p][c] * Wqkv[o][c] + Bqkv[o]   (BT form)
// BK=64, XCD swizzle.
// ---------------------------------------------------------------------------
__global__ __launch_bounds__(256) void gemm_qkv(
    ushort* __restrict__ Xt, ushort* __restrict__ Wqkv,
    const float* __restrict__ Bqkv, ushort* __restrict__ QKV)
{
    __shared__ __align__(16) ushort As[128 * 64];   // 16 KB
    __shared__ __align__(16) ushort Bs[128 * 64];   // 16 KB

    const int ord   = blockIdx.x;                    // 0..1535
    const int n_idx = (ord >> 3) % 6;
    const int g     = (ord & 7) + 8 * (ord / 48);    // m-tile 0..255
    const int m0    = g * 128;                       // p
    const int n0    = n_idx * 128;                   // o

    const int t     = threadIdx.x;
    const int lane  = t & 63;
    const int w     = t >> 6;
    const int wm    = (w & 1) * 64;
    const int wn    = (w >> 1) * 64;
    const int l16   = lane & 15;
    const int quad  = lane >> 4;
    const int srow8 = lane >> 3;
    const int scol8 = (lane & 7) * 8;

    f32x4 acc[4][4] = {};

    for (int k0 = 0; k0 < 256; k0 += 64) {
        #pragma unroll
        for (int j = 0; j < 4; ++j) {
            const int i = w * 4 + j;
            GLL16(Xt   + (size_t)(m0 + i * 8 + srow8) * 256 + k0 + scol8, As + i * 512);
            GLL16(Wqkv + (size_t)(n0 + i * 8 + srow8) * 256 + k0 + scol8, Bs + i * 512);
        }
        __syncthreads();
        #pragma unroll
        for (int s = 0; s < 2; ++s) {
            bf16x8 af[4], bfr[4];
            #pragma unroll
            for (int mi = 0; mi < 4; ++mi)
                af[mi] = *(const bf16x8*)(As + (wm + mi * 16 + l16) * 64 + s * 32 + quad * 8);
            #pragma unroll
            for (int ni = 0; ni < 4; ++ni)
                bfr[ni] = *(const bf16x8*)(Bs + (wn + ni * 16 + l16) * 64 + s * 32 + quad * 8);
            #pragma unroll
            for (int mi = 0; mi < 4; ++mi)
                #pragma unroll
                for (int ni = 0; ni < 4; ++ni)
                    acc[mi][ni] = __builtin_amdgcn_mfma_f32_16x16x32_bf16(
                        af[mi], bfr[ni], acc[mi][ni], 0, 0, 0);
        }
        __syncthreads();
    }

    #pragma unroll
    for (int ni = 0; ni < 4; ++ni) {
        const int og = n0 + wn + ni * 16 + l16;
        const float bias = Bqkv[og];
        #pragma unroll
        for (int mi = 0; mi < 4; ++mi)
            #pragma unroll
            for (int r = 0; r < 4; ++r) {
                const int pg = m0 + wm + mi * 16 + quad * 4 + r;
                QKV[(size_t)pg * O_QKV + og] = f2b(acc[mi][ni][r] + bias);
            }
    }
}

// ---------------------------------------------------------------------------
// attention: 8 pixels / 256-thread block. K+V of one source pixel are 1024
// CONTIGUOUS bytes in QKV -> one wave-wide global_load_lds per sample.
// Wave w stages+computes pixels {2w, 2w+1}: 18 async DMAs, one vmcnt(0),
// no result VGPRs (this defeats the RA-serialization seen in r4/r5).
// Softmax is computed redundantly per-thread (all quad lanes hold the full
// dot after 2 shuffles) -> no sc/at LDS, no post-score barriers.
// ---------------------------------------------------------------------------
__global__ __launch_bounds__(256) void attn_k(
    const float* __restrict__ grid, const ushort* __restrict__ QKV,
    ushort* __restrict__ Ab)
{
    __shared__ __align__(16) ushort KV[8 * 9 * 512];   // [pix][k][K(256)|V(256)] = 72 KB
    __shared__ int pk[8][9];

    const int t    = threadIdx.x;
    const int lane = t & 63;
    const int wid  = t >> 6;      // wave 0..3
    const int p0   = blockIdx.x * 8;

    if (t < 72) {
        const int pix = t / 9, k = t - pix * 9;
        const int p = p0 + pix;
        const int h = p >> 8, w = p & 255;
        const int kh = k / 3, kw = k - kh * 3;
        const int gr = (h * 3 + kh) * 768 + (w * 3 + kw);
        const float gx = grid[gr * 2 + 0];
        const float gy = grid[gr * 2 + 1];
        int ix = (int)rintf((gx + 1.0f) * 0.5f * 255.0f);
        int iy = (int)rintf((gy + 1.0f) * 0.5f * 127.0f);
        ix = min(max(ix, 0), 255);
        iy = min(max(iy, 0), 127);
        pk[pix][k] = iy * 256 + ix;
    }
    __syncthreads();

    // -------- DMA stage: 18 x 1KB per wave (K row + V row per sample) ------
    #pragma unroll
    for (int j = 0; j < 18; ++j) {
        const int pix = 2 * wid + (j >= 9);
        const int k   = (j >= 9) ? j - 9 : j;
        const size_t src = (size_t)pk[pix][k] * O_QKV + 256;   // K start; V follows
        GLL16(QKV + src + lane * 8, KV + (pix * 9 + k) * 512);
    }
    asm volatile("s_waitcnt vmcnt(0)" ::: "memory");

    // -------- compute (wave-local; no further block barriers) --------------
    const int pix = t >> 5;        // 0..7  (wave w -> pixels 2w, 2w+1)
    const int g   = t & 31;        // 8-channel group
    const int c8  = g * 8;
    const int p   = p0 + pix;

    const ushort8 q8 = *(const ushort8*)&QKV[(size_t)p * O_QKV + c8];

    float s[9];
    #pragma unroll
    for (int k = 0; k < 9; ++k) {
        const ushort8 k8 = *(const ushort8*)&KV[(pix * 9 + k) * 512 + c8];
        float d = 0.0f;
        #pragma unroll
        for (int i = 0; i < 8; ++i) d = fmaf(b2f(q8[i]), b2f(k8[i]), d);
        d += __shfl_xor(d, 1);
        d += __shfl_xor(d, 2);      // all 4 quad lanes now hold the head dot
        s[k] = d;
    }

    const float scale = 0.17677669529663687f;  // 32^-0.5
    float m = -1e30f;
    #pragma unroll
    for (int k = 0; k < 9; ++k) { s[k] *= scale; m = fmaxf(m, s[k]); }
    float sum = 0.0f;
    #pragma unroll
    for (int k = 0; k < 9; ++k) { s[k] = expf(s[k] - m); sum += s[k]; }
    const float inv = 1.0f / sum;

    float o[8] = {};
    #pragma unroll
    for (int k = 0; k < 9; ++k) {
        const float a = s[k] * inv;
        const ushort8 v8 = *(const ushort8*)&KV[(pix * 9 + k) * 512 + 256 + c8];
        #pragma unroll
        for (int i = 0; i < 8; ++i) o[i] = fmaf(a, b2f(v8[i]), o[i]);
    }
    ushort8 r;
    #pragma unroll
    for (int i = 0; i < 8; ++i) r[i] = f2b(o[i]);
    *(ushort8*)&Ab[(size_t)p * 256 + c8] = r;
}

// ---------------------------------------------------------------------------
// GEMM2: y[o][p] = sum_c Wo[o][c] * Ab[p][c] + bo[o].  BK=64.
// ---------------------------------------------------------------------------
__global__ __launch_bounds__(256) void gemm_out(
    ushort* __restrict__ Wo, ushort* __restrict__ Ab,
    const float* __restrict__ bo, float* __restrict__ y)
{
    __shared__ __align__(16) ushort As[128 * 64];
    __shared__ __align__(16) ushort Bs[128 * 64];

    const int ord   = blockIdx.x;                  // 0..511
    const int o_idx = (ord >> 3) & 1;
    const int p_idx = (ord & 7) + 8 * (ord >> 4);
    const int m0    = o_idx * 128;                 // o
    const int n0    = p_idx * 128;                 // p

    const int t     = threadIdx.x;
    const int lane  = t & 63;
    const int w     = t >> 6;
    const int wm    = (w & 1) * 64;
    const int wn    = (w >> 1) * 64;
    const int l16   = lane & 15;
    const int quad  = lane >> 4;
    const int srow8 = lane >> 3;
    const int scol8 = (lane & 7) * 8;

    f32x4 acc[4][4] = {};

    for (int k0 = 0; k0 < 256; k0 += 64) {
        #pragma unroll
        for (int j = 0; j < 4; ++j) {
            const int i = w * 4 + j;
            GLL16(Wo + (size_t)(m0 + i * 8 + srow8) * 256 + k0 + scol8, As + i * 512);
            GLL16(Ab + (size_t)(n0 + i * 8 + srow8) * 256 + k0 + scol8, Bs + i * 512);
        }
        __syncthreads();
        #pragma unroll
        for (int s = 0; s < 2; ++s) {
            bf16x8 af[4], bfr[4];
            #pragma unroll
            for (int mi = 0; mi < 4; ++mi)
                af[mi] = *(const bf16x8*)(As + (wm + mi * 16 + l16) * 64 + s * 32 + quad * 8);
            #pragma unroll
            for (int ni = 0; ni < 4; ++ni)
                bfr[ni] = *(const bf16x8*)(Bs + (wn + ni * 16 + l16) * 64 + s * 32 + quad * 8);
            #pragma unroll
            for (int mi = 0; mi < 4; ++mi)
                #pragma unroll
                for (int ni = 0; ni < 4; ++ni)
                    acc[mi][ni] = __builtin_amdgcn_mfma_f32_16x16x32_bf16(
                        af[mi], bfr[ni], acc[mi][ni], 0, 0, 0);
        }
        __syncthreads();
    }

    #pragma unroll
    for (int mi = 0; mi < 4; ++mi)
        #pragma unroll
        for (int r = 0; r < 4; ++r) {
            const int og = m0 + wm + mi * 16 + quad * 4 + r;
            const float bias = bo[og];
            #pragma unroll
            for (int ni = 0; ni < 4; ++ni) {
                const int pg = n0 + wn + ni * 16 + l16;
                y[(size_t)og * P_TOT + pg] = acc[mi][ni][r] + bias;
            }
        }
}

extern "C" void kernel_launch(void* const* d_in, const int* in_sizes, int n_in,
                              void* d_out, int out_size, void* d_ws, size_t ws_size,
                              hipStream_t stream) {
    const float* x    = (const float*)d_in[0];
    const float* grid = (const float*)d_in[1];
    const float* wq   = (const float*)d_in[2];
    const float* bq   = (const float*)d_in[3];
    const float* wk   = (const float*)d_in[4];
    const float* bk   = (const float*)d_in[5];
    const float* wv   = (const float*)d_in[6];
    const float* bv   = (const float*)d_in[7];
    const float* wo   = (const float*)d_in[8];
    const float* bo   = (const float*)d_in[9];
    float* y = (float*)d_out;

    ushort* Xt   = (ushort*)d_ws;                       // 16 MB
    ushort* QKV  = Xt  + (size_t)P_TOT * 256;           // 48 MB
    ushort* Ab   = QKV + (size_t)P_TOT * O_QKV;         // 16 MB
    ushort* Wqkv = Ab  + (size_t)P_TOT * 256;           // 384 KB
    ushort* Wo   = Wqkv + 768 * 256;                    // 128 KB
    float*  Bqkv = (float*)(Wo + 256 * 256);            // 3 KB

    prep_w<<<256, 256, 0, stream>>>(wq, wk, wv, wo, bq, bk, bv, Wqkv, Wo, Bqkv);
    transpose_x<<<dim3(P_TOT / 64, 4), 256, 0, stream>>>(x, Xt);
    gemm_qkv<<<1536, 256, 0, stream>>>(Xt, Wqkv, Bqkv, QKV);
    attn_k<<<P_TOT / 8, 256, 0, stream>>>(grid, QKV, Ab);
    gemm_out<<<512, 256, 0, stream>>>(Wo, Ab, bo, y);
}

// Round 7
// 176.198 us; speedup vs baseline: 1.0412x; 1.0412x over previous
//
#include <hip/hip_runtime.h>
#include <hip/hip_bf16.h>

#define P_TOT 32768   // H*W
#define O_QKV 768

using f32x4   = float  __attribute__((ext_vector_type(4)));
using bf16x8  = __bf16 __attribute__((ext_vector_type(8)));
using ushort8 = unsigned short __attribute__((ext_vector_type(8)));

typedef __attribute__((address_space(1))) void* gptr_t;
typedef __attribute__((address_space(3))) void* sptr_t;
// async global->LDS, 16B per lane, dest = uniform base + lane*16
#define GLL16(g, l) __builtin_amdgcn_global_load_lds((gptr_t)(g), (sptr_t)(l), 16, 0, 0)

__device__ __forceinline__ ushort f2b(float f) {
    __hip_bfloat16 h = __float2bfloat16(f);   // RNE
    return *reinterpret_cast<ushort*>(&h);
}
__device__ __forceinline__ float b2f(ushort u) {
    return __uint_as_float(((unsigned)u) << 16);   // exact
}

// ---------------------------------------------------------------------------
// fused prep + transpose:
//   all 2048 blocks: transpose x (256,32768) fp32 -> Xt (32768,256) bf16
//   blocks < 256 additionally: cast weights to bf16, pack biases
// ---------------------------------------------------------------------------
__global__ __launch_bounds__(256) void prep_transpose(
    const float* __restrict__ x, ushort* __restrict__ Xt,
    const float* __restrict__ wq, const float* __restrict__ wk,
    const float* __restrict__ wv, const float* __restrict__ wo,
    const float* __restrict__ bq, const float* __restrict__ bk,
    const float* __restrict__ bv,
    ushort* __restrict__ Wqkv, ushort* __restrict__ Wo, float* __restrict__ Bqkv)
{
    __shared__ float ts[64][65];
    const int bid = blockIdx.x;             // 0..2047
    const int p0 = (bid >> 2) * 64, c0 = (bid & 3) * 64;
    const int t = threadIdx.x;
    const int pl = t & 63, cl = t >> 6;
    #pragma unroll
    for (int i = 0; i < 16; ++i)
        ts[cl + 4 * i][pl] = x[(size_t)(c0 + cl + 4 * i) * P_TOT + p0 + pl];
    __syncthreads();
    const int pr = t >> 4, cc = (t & 15) * 4;
    #pragma unroll
    for (int i = 0; i < 4; ++i) {
        const int p = pr + 16 * i;
        ushort4 u;
        u.x = f2b(ts[cc + 0][p]); u.y = f2b(ts[cc + 1][p]);
        u.z = f2b(ts[cc + 2][p]); u.w = f2b(ts[cc + 3][p]);
        *(ushort4*)&Xt[(size_t)(p0 + p) * 256 + c0 + cc] = u;
    }
    if (bid < 256) {
        const int i = bid * 256 + t;
        Wqkv[i]          = f2b(wq[i]);
        Wqkv[65536 + i]  = f2b(wk[i]);
        Wqkv[131072 + i] = f2b(wv[i]);
        Wo[i]            = f2b(wo[i]);
        if (i < 256) { Bqkv[i] = bq[i]; Bqkv[256 + i] = bk[i]; Bqkv[512 + i] = bv[i]; }
    }
}

// ---------------------------------------------------------------------------
// GEMM1: QKV[p][o] = sum_c Xt[p][c] * Wqkv[o][c] + Bqkv[o]   (BT form)
// BK=64, XCD swizzle.
// ---------------------------------------------------------------------------
__global__ __launch_bounds__(256) void gemm_qkv(
    ushort* __restrict__ Xt, ushort* __restrict__ Wqkv,
    const float* __restrict__ Bqkv, ushort* __restrict__ QKV)
{
    __shared__ __align__(16) ushort As[128 * 64];   // 16 KB
    __shared__ __align__(16) ushort Bs[128 * 64];   // 16 KB

    const int ord   = blockIdx.x;                    // 0..1535
    const int n_idx = (ord >> 3) % 6;
    const int g     = (ord & 7) + 8 * (ord / 48);    // m-tile 0..255
    const int m0    = g * 128;                       // p
    const int n0    = n_idx * 128;                   // o

    const int t     = threadIdx.x;
    const int lane  = t & 63;
    const int w     = t >> 6;
    const int wm    = (w & 1) * 64;
    const int wn    = (w >> 1) * 64;
    const int l16   = lane & 15;
    const int quad  = lane >> 4;
    const int srow8 = lane >> 3;
    const int scol8 = (lane & 7) * 8;

    f32x4 acc[4][4] = {};

    for (int k0 = 0; k0 < 256; k0 += 64) {
        #pragma unroll
        for (int j = 0; j < 4; ++j) {
            const int i = w * 4 + j;
            GLL16(Xt   + (size_t)(m0 + i * 8 + srow8) * 256 + k0 + scol8, As + i * 512);
            GLL16(Wqkv + (size_t)(n0 + i * 8 + srow8) * 256 + k0 + scol8, Bs + i * 512);
        }
        __syncthreads();
        #pragma unroll
        for (int s = 0; s < 2; ++s) {
            bf16x8 af[4], bfr[4];
            #pragma unroll
            for (int mi = 0; mi < 4; ++mi)
                af[mi] = *(const bf16x8*)(As + (wm + mi * 16 + l16) * 64 + s * 32 + quad * 8);
            #pragma unroll
            for (int ni = 0; ni < 4; ++ni)
                bfr[ni] = *(const bf16x8*)(Bs + (wn + ni * 16 + l16) * 64 + s * 32 + quad * 8);
            #pragma unroll
            for (int mi = 0; mi < 4; ++mi)
                #pragma unroll
                for (int ni = 0; ni < 4; ++ni)
                    acc[mi][ni] = __builtin_amdgcn_mfma_f32_16x16x32_bf16(
                        af[mi], bfr[ni], acc[mi][ni], 0, 0, 0);
        }
        __syncthreads();
    }

    #pragma unroll
    for (int ni = 0; ni < 4; ++ni) {
        const int og = n0 + wn + ni * 16 + l16;
        const float bias = Bqkv[og];
        #pragma unroll
        for (int mi = 0; mi < 4; ++mi)
            #pragma unroll
            for (int r = 0; r < 4; ++r) {
                const int pg = m0 + wm + mi * 16 + quad * 4 + r;
                QKV[(size_t)pg * O_QKV + og] = f2b(acc[mi][ni][r] + bias);
            }
    }
}

// ---------------------------------------------------------------------------
// attention: barrier-free, one wave per pixel (4 pixels / 256-thread block).
// Lane half 0 owns samples 0..4; half 1 owns 4..8 (sample 4 weight-zeroed in
// half 1). Per-thread gather payload = 10 x ushort8 (~40 VGPRs) -> fits the
// allocator budget without the r4/r5 serialization. Softmax merged across
// halves via shfl_xor(.,32). pk computed per-lane (wave-uniform) -> no LDS.
// ---------------------------------------------------------------------------
__global__ __launch_bounds__(256) void attn_k(
    const float* __restrict__ grid, const ushort* __restrict__ QKV,
    ushort* __restrict__ Ab)
{
    const int t    = threadIdx.x;
    const int wid  = t >> 6;       // wave = pixel
    const int lane = t & 63;
    const int half = lane >> 5;    // 0: k=0..4, 1: k=4..8
    const int g    = lane & 31;    // 8-channel group
    const int c8   = g * 8;
    const int p    = blockIdx.x * 4 + wid;
    const int h    = p >> 8, w = p & 255;

    // per-lane (wave-uniform) gather indices
    int pk[9];
    #pragma unroll
    for (int k = 0; k < 9; ++k) {
        const int kh = k / 3, kw = k - kh * 3;
        const int gr = (h * 3 + kh) * 768 + (w * 3 + kw);
        const float gx = grid[gr * 2 + 0];
        const float gy = grid[gr * 2 + 1];
        int ix = (int)rintf((gx + 1.0f) * 0.5f * 255.0f);
        int iy = (int)rintf((gy + 1.0f) * 0.5f * 127.0f);
        ix = min(max(ix, 0), 255);
        iy = min(max(iy, 0), 127);
        pk[k] = iy * 256 + ix;
    }

    const ushort8 q8 = *(const ushort8*)&QKV[(size_t)p * O_QKV + c8];

    const int kb = half * 4;       // sample base for this half
    ushort8 k8[5], v8[5];
    #pragma unroll
    for (int j = 0; j < 5; ++j) {
        const size_t base = (size_t)pk[kb + j] * O_QKV + c8;
        k8[j] = *(const ushort8*)&QKV[base + 256];
        v8[j] = *(const ushort8*)&QKV[base + 512];
    }

    const float scale = 0.17677669529663687f;  // 32^-0.5
    float e[5], m = -1e30f;
    #pragma unroll
    for (int j = 0; j < 5; ++j) {
        float d = 0.0f;
        #pragma unroll
        for (int i = 0; i < 8; ++i) d = fmaf(b2f(q8[i]), b2f(k8[j][i]), d);
        d += __shfl_xor(d, 1);
        d += __shfl_xor(d, 2);      // quad = one head: full 32-ch dot
        e[j] = d * scale;
        m = fmaxf(m, e[j]);
    }
    m = fmaxf(m, __shfl_xor(m, 32));   // global max over all 9

    float sum = 0.0f;
    #pragma unroll
    for (int j = 0; j < 5; ++j) {
        e[j] = expf(e[j] - m);
        if (!(half == 1 && j == 0)) sum += e[j];   // exclude duplicate k=4
    }
    sum += __shfl_xor(sum, 32);
    const float inv = 1.0f / sum;

    float o[8] = {};
    #pragma unroll
    for (int j = 0; j < 5; ++j) {
        const float a = (half == 1 && j == 0) ? 0.0f : e[j] * inv;
        #pragma unroll
        for (int i = 0; i < 8; ++i) o[i] = fmaf(a, b2f(v8[j][i]), o[i]);
    }
    ushort8 r;
    #pragma unroll
    for (int i = 0; i < 8; ++i) r[i] = f2b(o[i] + __shfl_xor(o[i], 32));
    if (half == 0)
        *(ushort8*)&Ab[(size_t)p * 256 + c8] = r;
}

// ---------------------------------------------------------------------------
// GEMM2: y[o][p] = sum_c Wo[o][c] * Ab[p][c] + bo[o].  BK=64.
// ---------------------------------------------------------------------------
__global__ __launch_bounds__(256) void gemm_out(
    ushort* __restrict__ Wo, ushort* __restrict__ Ab,
    const float* __restrict__ bo, float* __restrict__ y)
{
    __shared__ __align__(16) ushort As[128 * 64];
    __shared__ __align__(16) ushort Bs[128 * 64];

    const int ord   = blockIdx.x;                  // 0..511
    const int o_idx = (ord >> 3) & 1;
    const int p_idx = (ord & 7) + 8 * (ord >> 4);
    const int m0    = o_idx * 128;                 // o
    const int n0    = p_idx * 128;                 // p

    const int t     = threadIdx.x;
    const int lane  = t & 63;
    const int w     = t >> 6;
    const int wm    = (w & 1) * 64;
    const int wn    = (w >> 1) * 64;
    const int l16   = lane & 15;
    const int quad  = lane >> 4;
    const int srow8 = lane >> 3;
    const int scol8 = (lane & 7) * 8;

    f32x4 acc[4][4] = {};

    for (int k0 = 0; k0 < 256; k0 += 64) {
        #pragma unroll
        for (int j = 0; j < 4; ++j) {
            const int i = w * 4 + j;
            GLL16(Wo + (size_t)(m0 + i * 8 + srow8) * 256 + k0 + scol8, As + i * 512);
            GLL16(Ab + (size_t)(n0 + i * 8 + srow8) * 256 + k0 + scol8, Bs + i * 512);
        }
        __syncthreads();
        #pragma unroll
        for (int s = 0; s < 2; ++s) {
            bf16x8 af[4], bfr[4];
            #pragma unroll
            for (int mi = 0; mi < 4; ++mi)
                af[mi] = *(const bf16x8*)(As + (wm + mi * 16 + l16) * 64 + s * 32 + quad * 8);
            #pragma unroll
            for (int ni = 0; ni < 4; ++ni)
                bfr[ni] = *(const bf16x8*)(Bs + (wn + ni * 16 + l16) * 64 + s * 32 + quad * 8);
            #pragma unroll
            for (int mi = 0; mi < 4; ++mi)
                #pragma unroll
                for (int ni = 0; ni < 4; ++ni)
                    acc[mi][ni] = __builtin_amdgcn_mfma_f32_16x16x32_bf16(
                        af[mi], bfr[ni], acc[mi][ni], 0, 0, 0);
        }
        __syncthreads();
    }

    #pragma unroll
    for (int mi = 0; mi < 4; ++mi)
        #pragma unroll
        for (int r = 0; r < 4; ++r) {
            const int og = m0 + wm + mi * 16 + quad * 4 + r;
            const float bias = bo[og];
            #pragma unroll
            for (int ni = 0; ni < 4; ++ni) {
                const int pg = n0 + wn + ni * 16 + l16;
                y[(size_t)og * P_TOT + pg] = acc[mi][ni][r] + bias;
            }
        }
}

extern "C" void kernel_launch(void* const* d_in, const int* in_sizes, int n_in,
                              void* d_out, int out_size, void* d_ws, size_t ws_size,
                              hipStream_t stream) {
    const float* x    = (const float*)d_in[0];
    const float* grid = (const float*)d_in[1];
    const float* wq   = (const float*)d_in[2];
    const float* bq   = (const float*)d_in[3];
    const float* wk   = (const float*)d_in[4];
    const float* bk   = (const float*)d_in[5];
    const float* wv   = (const float*)d_in[6];
    const float* bv   = (const float*)d_in[7];
    const float* wo   = (const float*)d_in[8];
    const float* bo   = (const float*)d_in[9];
    float* y = (float*)d_out;

    ushort* Xt   = (ushort*)d_ws;                       // 16 MB
    ushort* QKV  = Xt  + (size_t)P_TOT * 256;           // 48 MB
    ushort* Ab   = QKV + (size_t)P_TOT * O_QKV;         // 16 MB
    ushort* Wqkv = Ab  + (size_t)P_TOT * 256;           // 384 KB
    ushort* Wo   = Wqkv + 768 * 256;                    // 128 KB
    float*  Bqkv = (float*)(Wo + 256 * 256);            // 3 KB

    prep_transpose<<<2048, 256, 0, stream>>>(x, Xt, wq, wk, wv, wo, bq, bk, bv,
                                             Wqkv, Wo, Bqkv);
    gemm_qkv<<<1536, 256, 0, stream>>>(Xt, Wqkv, Bqkv, QKV);
    attn_k<<<P_TOT / 4, 256, 0, stream>>>(grid, QKV, Ab);
    gemm_out<<<512, 256, 0, stream>>>(Wo, Ab, bo, y);
}